// Round 10
// baseline (110.216 us; speedup 1.0000x reference)
//
#include <hip/hip_runtime.h>
#include <cstdint>
#include <cstddef>

typedef __attribute__((ext_vector_type(4))) int i32x4;
typedef __attribute__((ext_vector_type(4))) float f32x4;

#define BM 16          // rows per tile
#define NT 8           // tiles per block (block owns 128 rows)
#define XSTRIDE 848    // LDS bytes/row for xq
#define HSTRIDE 272    // LDS bytes/row for hq
#define ROWB 3136      // bytes per x row
#define WROWS 6272     // 2 rows per wave staged via DMA (wave-local span)

static __device__ __forceinline__ void gload_lds16(const void* g, void* l) {
    __builtin_amdgcn_global_load_lds((__attribute__((address_space(1))) void*)g,
                                     (__attribute__((address_space(3))) void*)l, 16, 0, 0);
}

static __device__ __forceinline__ int q4ri(f32x4 v, float ri) {
    float a = fminf(fmaxf(rintf(v.x * ri), -127.f), 127.f);
    float b = fminf(fmaxf(rintf(v.y * ri), -127.f), 127.f);
    float c = fminf(fmaxf(rintf(v.z * ri), -127.f), 127.f);
    float d = fminf(fmaxf(rintf(v.w * ri), -127.f), 127.f);
    return ((int)a & 255) | (((int)b & 255) << 8) | (((int)c & 255) << 16) | (((int)d & 255) << 24);
}
static __device__ __forceinline__ int q4div(f32x4 v, float s) {
    float a = fminf(fmaxf(rintf(v.x / s), -127.f), 127.f);
    float b = fminf(fmaxf(rintf(v.y / s), -127.f), 127.f);
    float c = fminf(fmaxf(rintf(v.z / s), -127.f), 127.f);
    float d = fminf(fmaxf(rintf(v.w / s), -127.f), 127.f);
    return ((int)a & 255) | (((int)b & 255) << 8) | (((int)c & 255) << 16) | (((int)d & 255) << 24);
}
static __device__ __forceinline__ float max4abs(f32x4 v) {
    return fmaxf(fmaxf(fabsf(v.x), fabsf(v.y)), fmaxf(fabsf(v.z), fabsf(v.w)));
}

// ---------------- weight quantization (tiny, runs once per call) --------------
__global__ __launch_bounds__(64) void quantW(const float* __restrict__ W1,
                                             const float* __restrict__ W2,
                                             int8_t* __restrict__ W1q, float* __restrict__ W1s,
                                             int8_t* __restrict__ W2q, float* __restrict__ W2s) {
    const int l = threadIdx.x;
    const int b = blockIdx.x;
    if (b < 256) {
        const float* wr = W1 + (size_t)b * 784;
        f32x4 v0 = *(const f32x4*)(wr + 4 * l);
        f32x4 v1 = *(const f32x4*)(wr + 4 * (l + 64));
        f32x4 v2 = *(const f32x4*)(wr + 4 * (l + 128));
        f32x4 v3 = (f32x4){0.f, 0.f, 0.f, 0.f};
        if (l < 4) v3 = *(const f32x4*)(wr + 4 * (192 + l));
        float m = fmaxf(fmaxf(max4abs(v0), max4abs(v1)), fmaxf(max4abs(v2), max4abs(v3)));
        #pragma unroll
        for (int off = 32; off >= 1; off >>= 1) m = fmaxf(m, __shfl_xor(m, off));
        float s = (m == 0.f) ? 1.f : m / 127.f;
        int* ow = (int*)(W1q + (size_t)b * 832);
        ow[l] = q4div(v0, s);
        ow[l + 64] = q4div(v1, s);
        ow[l + 128] = q4div(v2, s);
        if (l < 4) ow[192 + l] = q4div(v3, s);
        if (l >= 16 && l < 28) ow[196 + (l - 16)] = 0;
        if (l == 0) W1s[b] = s;
    } else {
        const int r = b - 256;
        int* ow = (int*)(W2q + (size_t)r * 256);
        if (r < 10) {
            f32x4 v0 = *(const f32x4*)(W2 + (size_t)r * 256 + 4 * l);
            float m = max4abs(v0);
            #pragma unroll
            for (int off = 32; off >= 1; off >>= 1) m = fmaxf(m, __shfl_xor(m, off));
            float s = (m == 0.f) ? 1.f : m / 127.f;
            ow[l] = q4div(v0, s);
            if (l == 0) W2s[r] = s;
        } else {
            ow[l] = 0;
            if (l == 0) W2s[r] = 1.f;
        }
    }
}

// ---- fused MLP, persistent 2-block/CU, cross-tile pipelined streaming -------
// 256 threads (4 waves), BM=16, NT=8. While tile t computes, tile t+1 streams:
// rows 8..15 via WAVE-LOCAL global_load_lds DMA (wave w stages AND quantizes
// rows 8+2w..8+2w+1 — its own vmcnt covers its own reads), rows 0..7 via
// register staging (issued post-K-loop). Double-buffered xq. ~58 KB LDS.
__global__ __launch_bounds__(256, 4) void fused_mlp(
    const float* __restrict__ x,
    const int8_t* __restrict__ W1q, const float* __restrict__ W1s, const float* __restrict__ b1,
    const int8_t* __restrict__ W2q, const float* __restrict__ W2s, const float* __restrict__ b2,
    float* __restrict__ out)
{
    __shared__ __align__(16) int8_t xq[2][BM * XSTRIDE];  // 2 x 13568 B
    __shared__ __align__(16) int8_t hq[BM * HSTRIDE];     // 4352 B
    __shared__ __align__(16) int8_t stage[4 * WROWS];     // 25088 B (rows 8..15, f32)
    __shared__ float sxs[2][BM];
    __shared__ float s2s[BM];
    __shared__ float hpart[4][BM];
    __shared__ float b1s[256], w1ss[256];
    __shared__ float b2s[16], w2ss[16];

    const int tid = threadIdx.x;
    const int l = tid & 63;
    const int w = tid >> 6;          // wave 0..3
    const int g = l >> 4;            // 16-lane group
    const int lr = l & 15;
    const size_t blk0 = (size_t)blockIdx.x * (BM * NT);
    const char* xb = (const char*)x;

    b1s[tid] = b1[tid];
    w1ss[tid] = W1s[tid];
    if (tid < 16) { w2ss[tid] = W2s[tid]; b2s[tid] = (tid < 10) ? b2[tid] : 0.f; }

    char* const sdst = (char*)stage + w * WROWS;   // this wave's private stage span

    f32x4 R[2][3], Rt[2];   // register staging: 2 rows/wave of the next tile

    // ================= prologue: stage + quantize tile 0 =================
    {
        // DMA rows 8+2w, 8+2w+1 of tile 0 (wave-local: 6272 B contiguous)
        const char* src = xb + (blk0 + 8 + 2 * w) * ROWB;
        #pragma unroll
        for (int i = 0; i < 6; ++i)
            gload_lds16(src + i * 1024 + l * 16, sdst + i * 1024);
        if (l < 8) gload_lds16(src + 6144 + l * 16, sdst + 6144);
        // register rows 2w, 2w+1 of tile 0
        #pragma unroll
        for (int j = 0; j < 2; ++j) {
            const float* xr = x + (blk0 + 2 * w + j) * 784;
            R[j][0] = *(const f32x4*)(xr + 4 * l);
            R[j][1] = *(const f32x4*)(xr + 256 + 4 * l);
            R[j][2] = *(const f32x4*)(xr + 512 + 4 * l);
            Rt[j] = (f32x4){0.f, 0.f, 0.f, 0.f};
            if (l < 4) Rt[j] = *(const f32x4*)(xr + 768 + 4 * l);
        }
        __builtin_amdgcn_sched_barrier(0);
        // quantize register rows
        #pragma unroll
        for (int j = 0; j < 2; ++j) {
            const int row = 2 * w + j;
            float m = fmaxf(fmaxf(max4abs(R[j][0]), max4abs(R[j][1])),
                            fmaxf(max4abs(R[j][2]), max4abs(Rt[j])));
            #pragma unroll
            for (int off = 32; off >= 1; off >>= 1) m = fmaxf(m, __shfl_xor(m, off));
            float s = (m == 0.f) ? 1.f : m / 127.f;
            float ri = 1.f / s;
            int* xw = (int*)(xq[0] + row * XSTRIDE);
            xw[l] = q4ri(R[j][0], ri);
            xw[l + 64] = q4ri(R[j][1], ri);
            xw[l + 128] = q4ri(R[j][2], ri);
            if (l < 4) xw[192 + l] = q4ri(Rt[j], ri);
            if (l >= 16 && l < 32) xw[196 + (l - 16)] = 0;
            if (l == 0) sxs[0][row] = s;
        }
        // quantize own DMA rows
        asm volatile("s_waitcnt vmcnt(0)" ::: "memory");
        __builtin_amdgcn_sched_barrier(0);
        #pragma unroll
        for (int j = 0; j < 2; ++j) {
            const int row = 8 + 2 * w + j;
            const float* sp = (const float*)(sdst + j * ROWB);
            f32x4 v0 = *(const f32x4*)(sp + 4 * l);
            f32x4 v1 = *(const f32x4*)(sp + 256 + 4 * l);
            f32x4 v2 = *(const f32x4*)(sp + 512 + 4 * l);
            f32x4 v3 = (f32x4){0.f, 0.f, 0.f, 0.f};
            if (l < 4) v3 = *(const f32x4*)(sp + 768 + 4 * l);
            float m = fmaxf(fmaxf(max4abs(v0), max4abs(v1)), fmaxf(max4abs(v2), max4abs(v3)));
            #pragma unroll
            for (int off = 32; off >= 1; off >>= 1) m = fmaxf(m, __shfl_xor(m, off));
            float s = (m == 0.f) ? 1.f : m / 127.f;
            float ri = 1.f / s;
            int* xw = (int*)(xq[0] + row * XSTRIDE);
            xw[l] = q4ri(v0, ri);
            xw[l + 64] = q4ri(v1, ri);
            xw[l + 128] = q4ri(v2, ri);
            if (l < 4) xw[192 + l] = q4ri(v3, ri);
            if (l >= 16 && l < 32) xw[196 + (l - 16)] = 0;
            if (l == 0) sxs[0][row] = s;
        }
    }
    __syncthreads();

    // ========================== main tile loop ==========================
    for (int t = 0; t < NT; ++t) {
        const int cur = t & 1;
        const int nxt = cur ^ 1;
        const size_t row0 = blk0 + (size_t)t * BM;
        const size_t nrow0 = row0 + BM;
        const bool more = (t + 1 < NT);

        // ---- issue DMA for next tile rows 8+2w..8+2w+1 (wave-local) ----
        if (more) {
            const char* src = xb + (nrow0 + 8 + 2 * w) * ROWB;
            #pragma unroll
            for (int i = 0; i < 6; ++i)
                gload_lds16(src + i * 1024 + l * 16, sdst + i * 1024);
            if (l < 8) gload_lds16(src + 6144 + l * 16, sdst + 6144);
        }
        __builtin_amdgcn_sched_barrier(0);

        // ---- GEMM1: wave w owns cols w*64..w*64+63, rows 0..15 ----
        i32x4 acc[4];
        #pragma unroll
        for (int nt = 0; nt < 4; ++nt) acc[nt] = (i32x4){0, 0, 0, 0};

        const int8_t* xbase = xq[cur] + lr * XSTRIDE + g * 16;
        const int8_t* wbase = W1q + (size_t)(w * 64 + lr) * 832 + g * 16;

        #pragma unroll
        for (int kk = 0; kk < 13; ++kk) {
            const int ko = kk * 64;
            i32x4 a = *(const i32x4*)(xbase + ko);
            i32x4 bv[4];
            #pragma unroll
            for (int nt = 0; nt < 4; ++nt) bv[nt] = *(const i32x4*)(wbase + (size_t)nt * 16 * 832 + ko);
            #pragma unroll
            for (int nt = 0; nt < 4; ++nt)
                acc[nt] = __builtin_amdgcn_mfma_i32_16x16x64_i8(a, bv[nt], acc[nt], 0, 0, 0);
        }

        // ---- issue register loads for next tile rows 2w, 2w+1 ----
        if (more) {
            #pragma unroll
            for (int j = 0; j < 2; ++j) {
                const float* xr = x + (nrow0 + 2 * w + j) * 784;
                R[j][0] = *(const f32x4*)(xr + 4 * l);
                R[j][1] = *(const f32x4*)(xr + 256 + 4 * l);
                R[j][2] = *(const f32x4*)(xr + 512 + 4 * l);
                Rt[j] = (f32x4){0.f, 0.f, 0.f, 0.f};
                if (l < 4) Rt[j] = *(const f32x4*)(xr + 768 + 4 * l);
            }
        }
        __builtin_amdgcn_sched_barrier(0);

        // ---- dequant + bias + relu ----
        float h[4][4];   // [reg r][nt]
        #pragma unroll
        for (int nt = 0; nt < 4; ++nt)
            #pragma unroll
            for (int r = 0; r < 4; ++r) {
                const int rowl = g * 4 + r;
                const int coll = w * 64 + nt * 16 + lr;
                float v = sxs[cur][rowl] * w1ss[coll] * (float)acc[nt][r] + b1s[coll];
                h[r][nt] = fmaxf(v, 0.f);
            }

        // ---- per-row max over this wave's 64 cols ----
        #pragma unroll
        for (int r = 0; r < 4; ++r) {
            float m = fmaxf(fmaxf(h[r][0], h[r][1]), fmaxf(h[r][2], h[r][3]));
            m = fmaxf(m, __shfl_xor(m, 1));
            m = fmaxf(m, __shfl_xor(m, 2));
            m = fmaxf(m, __shfl_xor(m, 4));
            m = fmaxf(m, __shfl_xor(m, 8));
            if (lr == 0) hpart[w][g * 4 + r] = m;
        }
        __syncthreads();   // BAR1

        // ---- requantize h into hq ----
        #pragma unroll
        for (int r = 0; r < 4; ++r) {
            const int rowl = g * 4 + r;
            float hm = fmaxf(fmaxf(hpart[0][rowl], hpart[1][rowl]),
                             fmaxf(hpart[2][rowl], hpart[3][rowl]));
            float s2 = (hm == 0.f) ? 1.f : hm / 127.f;
            float ri2 = 1.f / s2;
            if (w == 0 && lr == 0) s2s[rowl] = s2;
            #pragma unroll
            for (int nt = 0; nt < 4; ++nt) {
                float q = fminf(fmaxf(rintf(h[r][nt] * ri2), -127.f), 127.f);
                hq[rowl * HSTRIDE + w * 64 + nt * 16 + lr] = (int8_t)(int)q;
            }
        }
        __syncthreads();   // BAR2

        // ---- GEMM2 (wave 0) + epilogue ----
        if (w == 0) {
            i32x4 acc2 = (i32x4){0, 0, 0, 0};
            const int8_t* hbase = hq + lr * HSTRIDE + g * 16;
            const int8_t* w2base = W2q + lr * 256 + g * 16;
            #pragma unroll
            for (int kk = 0; kk < 4; ++kk) {
                i32x4 av = *(const i32x4*)(hbase + kk * 64);
                i32x4 bv = *(const i32x4*)(w2base + kk * 64);
                acc2 = __builtin_amdgcn_mfma_i32_16x16x64_i8(av, bv, acc2, 0, 0, 0);
            }
            if (lr < 10) {
                #pragma unroll
                for (int r = 0; r < 4; ++r) {
                    const int rowl = g * 4 + r;
                    float v = s2s[rowl] * w2ss[lr] * (float)acc2[r] + b2s[lr];
                    out[(row0 + rowl) * 10 + lr] = v;
                }
            }
        }

        // ---- quantize next tile into xq[nxt] ----
        if (more) {
            // register rows (loads issued right after GEMM1's K-loop)
            #pragma unroll
            for (int j = 0; j < 2; ++j) {
                const int row = 2 * w + j;
                float m = fmaxf(fmaxf(max4abs(R[j][0]), max4abs(R[j][1])),
                                fmaxf(max4abs(R[j][2]), max4abs(Rt[j])));
                #pragma unroll
                for (int off = 32; off >= 1; off >>= 1) m = fmaxf(m, __shfl_xor(m, off));
                float s = (m == 0.f) ? 1.f : m / 127.f;
                float ri = 1.f / s;
                int* xw = (int*)(xq[nxt] + row * XSTRIDE);
                xw[l] = q4ri(R[j][0], ri);
                xw[l + 64] = q4ri(R[j][1], ri);
                xw[l + 128] = q4ri(R[j][2], ri);
                if (l < 4) xw[192 + l] = q4ri(Rt[j], ri);
                if (l >= 16 && l < 32) xw[196 + (l - 16)] = 0;
                if (l == 0) sxs[nxt][row] = s;
            }
            // own DMA rows (issued before GEMM1; own vmcnt covers own span)
            asm volatile("s_waitcnt vmcnt(0)" ::: "memory");
            __builtin_amdgcn_sched_barrier(0);
            #pragma unroll
            for (int j = 0; j < 2; ++j) {
                const int row = 8 + 2 * w + j;
                const float* sp = (const float*)(sdst + j * ROWB);
                f32x4 v0 = *(const f32x4*)(sp + 4 * l);
                f32x4 v1 = *(const f32x4*)(sp + 256 + 4 * l);
                f32x4 v2 = *(const f32x4*)(sp + 512 + 4 * l);
                f32x4 v3 = (f32x4){0.f, 0.f, 0.f, 0.f};
                if (l < 4) v3 = *(const f32x4*)(sp + 768 + 4 * l);
                float m = fmaxf(fmaxf(max4abs(v0), max4abs(v1)), fmaxf(max4abs(v2), max4abs(v3)));
                #pragma unroll
                for (int off = 32; off >= 1; off >>= 1) m = fmaxf(m, __shfl_xor(m, off));
                float s = (m == 0.f) ? 1.f : m / 127.f;
                float ri = 1.f / s;
                int* xw = (int*)(xq[nxt] + row * XSTRIDE);
                xw[l] = q4ri(v0, ri);
                xw[l + 64] = q4ri(v1, ri);
                xw[l + 128] = q4ri(v2, ri);
                if (l < 4) xw[192 + l] = q4ri(v3, ri);
                if (l >= 16 && l < 32) xw[196 + (l - 16)] = 0;
                if (l == 0) sxs[nxt][row] = s;
            }
        }
        __syncthreads();   // BAR3
    }
}

extern "C" void kernel_launch(void* const* d_in, const int* in_sizes, int n_in,
                              void* d_out, int out_size, void* d_ws, size_t ws_size,
                              hipStream_t stream) {
    const float* x  = (const float*)d_in[0];
    const float* W1 = (const float*)d_in[1];
    const float* b1 = (const float*)d_in[2];
    const float* W2 = (const float*)d_in[3];
    const float* b2 = (const float*)d_in[4];
    float* out = (float*)d_out;

    int8_t* ws = (int8_t*)d_ws;
    int8_t* W1q = ws;                            // 256*832   = 212992 B
    float*  W1s = (float*)(ws + 212992);         // 1024 B
    int8_t* W2q = ws + 214016;                   // 4096 B
    float*  W2s = (float*)(ws + 218112);         // 64 B

    quantW<<<272, 64, 0, stream>>>(W1, W2, W1q, W1s, W2q, W2s);
    fused_mlp<<<512, 256, 0, stream>>>(x, W1q, W1s, b1, W2q, W2s, b2, out);
}

// Round 11
// 89.752 us; speedup vs baseline: 1.2280x; 1.2280x over previous
//
#include <hip/hip_runtime.h>
#include <cstdint>
#include <cstddef>

typedef __attribute__((ext_vector_type(4))) int i32x4;
typedef __attribute__((ext_vector_type(4))) float f32x4;

#define BM 64
#define XSTRIDE 848   // LDS bytes/row for xq tile (K-pad zeros to 832, stride pad to 848)
#define HSTRIDE 272   // LDS bytes/row for hq tile

static __device__ __forceinline__ int q4ri(f32x4 v, float ri) {
    float a = fminf(fmaxf(rintf(v.x * ri), -127.f), 127.f);
    float b = fminf(fmaxf(rintf(v.y * ri), -127.f), 127.f);
    float c = fminf(fmaxf(rintf(v.z * ri), -127.f), 127.f);
    float d = fminf(fmaxf(rintf(v.w * ri), -127.f), 127.f);
    return ((int)a & 255) | (((int)b & 255) << 8) | (((int)c & 255) << 16) | (((int)d & 255) << 24);
}
static __device__ __forceinline__ int q4div(f32x4 v, float s) {
    float a = fminf(fmaxf(rintf(v.x / s), -127.f), 127.f);
    float b = fminf(fmaxf(rintf(v.y / s), -127.f), 127.f);
    float c = fminf(fmaxf(rintf(v.z / s), -127.f), 127.f);
    float d = fminf(fmaxf(rintf(v.w / s), -127.f), 127.f);
    return ((int)a & 255) | (((int)b & 255) << 8) | (((int)c & 255) << 16) | (((int)d & 255) << 24);
}
static __device__ __forceinline__ float max4abs(f32x4 v) {
    return fmaxf(fmaxf(fabsf(v.x), fabsf(v.y)), fmaxf(fabsf(v.z), fabsf(v.w)));
}

// ---------------- weight quantization (tiny, runs once per call) --------------
__global__ __launch_bounds__(64) void quantW(const float* __restrict__ W1,
                                             const float* __restrict__ W2,
                                             int8_t* __restrict__ W1q, float* __restrict__ W1s,
                                             int8_t* __restrict__ W2q, float* __restrict__ W2s) {
    const int l = threadIdx.x;
    const int b = blockIdx.x;
    if (b < 256) {
        const float* wr = W1 + (size_t)b * 784;
        f32x4 v0 = *(const f32x4*)(wr + 4 * l);
        f32x4 v1 = *(const f32x4*)(wr + 4 * (l + 64));
        f32x4 v2 = *(const f32x4*)(wr + 4 * (l + 128));
        f32x4 v3 = (f32x4){0.f, 0.f, 0.f, 0.f};
        if (l < 4) v3 = *(const f32x4*)(wr + 4 * (192 + l));
        float m = fmaxf(fmaxf(max4abs(v0), max4abs(v1)), fmaxf(max4abs(v2), max4abs(v3)));
        #pragma unroll
        for (int off = 32; off >= 1; off >>= 1) m = fmaxf(m, __shfl_xor(m, off));
        float s = (m == 0.f) ? 1.f : m / 127.f;
        int* ow = (int*)(W1q + (size_t)b * 832);
        ow[l] = q4div(v0, s);
        ow[l + 64] = q4div(v1, s);
        ow[l + 128] = q4div(v2, s);
        if (l < 4) ow[192 + l] = q4div(v3, s);
        if (l >= 16 && l < 28) ow[196 + (l - 16)] = 0;
        if (l == 0) W1s[b] = s;
    } else {
        const int r = b - 256;
        int* ow = (int*)(W2q + (size_t)r * 256);
        if (r < 10) {
            f32x4 v0 = *(const f32x4*)(W2 + (size_t)r * 256 + 4 * l);
            float m = max4abs(v0);
            #pragma unroll
            for (int off = 32; off >= 1; off >>= 1) m = fmaxf(m, __shfl_xor(m, off));
            float s = (m == 0.f) ? 1.f : m / 127.f;
            ow[l] = q4div(v0, s);
            if (l == 0) W2s[r] = s;
        } else {
            ow[l] = 0;
            if (l == 0) W2s[r] = 1.f;
        }
    }
}

// ---------------- kernel A: pure-streaming x quantization --------------------
// No LDS, no barriers, ~40 VGPR -> 32 waves/CU. Structurally identical to a
// copy bench: batched independent loads, independent waves. One row per wave
// per iteration; 8192 waves grid-stride over 65536 rows.
__global__ __launch_bounds__(256) void quantX(const float* __restrict__ x,
                                              int8_t* __restrict__ xqg,
                                              float* __restrict__ xs) {
    const int l = threadIdx.x & 63;
    const int wid = (blockIdx.x << 2) + (threadIdx.x >> 6);   // 0..8191
    for (int row = wid; row < 65536; row += 8192) {
        const float* xr = x + (size_t)row * 784;
        f32x4 v0 = *(const f32x4*)(xr + 4 * l);
        f32x4 v1 = *(const f32x4*)(xr + 256 + 4 * l);
        f32x4 v2 = *(const f32x4*)(xr + 512 + 4 * l);
        f32x4 v3 = (f32x4){0.f, 0.f, 0.f, 0.f};
        if (l < 4) v3 = *(const f32x4*)(xr + 768 + 4 * l);
        float m = fmaxf(fmaxf(max4abs(v0), max4abs(v1)), fmaxf(max4abs(v2), max4abs(v3)));
        #pragma unroll
        for (int off = 32; off >= 1; off >>= 1) m = fmaxf(m, __shfl_xor(m, off));
        float s = (m == 0.f) ? 1.f : m / 127.f;
        float ri = 1.f / s;
        int* q = (int*)(xqg + (size_t)row * 784);
        q[l] = q4ri(v0, ri);
        q[l + 64] = q4ri(v1, ri);
        q[l + 128] = q4ri(v2, ri);
        if (l < 4) q[192 + l] = q4ri(v3, ri);
        if (l == 0) xs[row] = s;
    }
}

// ---------------- kernel B: int8 MLP from the global xq intermediate ---------
// 256 threads (4 waves), BM=64, LDS ~74 KB -> 2 blocks/CU. Stage xq tile
// (L3-hot, 50 KB) into padded LDS, then round-1's proven GEMM1 -> relu +
// requant -> GEMM2 -> store.
__global__ __launch_bounds__(256) void mlp(
    const int8_t* __restrict__ xqg, const float* __restrict__ xs,
    const int8_t* __restrict__ W1q, const float* __restrict__ W1s, const float* __restrict__ b1,
    const int8_t* __restrict__ W2q, const float* __restrict__ W2s, const float* __restrict__ b2,
    float* __restrict__ out)
{
    __shared__ __align__(16) int8_t xq[BM * XSTRIDE];   // 54272 B
    __shared__ __align__(16) int8_t hq[BM * HSTRIDE];   // 17408 B
    __shared__ float sxs[BM];
    __shared__ float hpart[4][BM];
    __shared__ float s2s[BM];
    __shared__ float b1s[256], w1ss[256];
    __shared__ float b2s[16], w2ss[16];

    const int t = threadIdx.x;
    const int l = t & 63;
    const int w = t >> 6;            // wave 0..3
    const int g = l >> 4;            // 16-lane group 0..3
    const int lr = l & 15;
    const size_t row0 = (size_t)blockIdx.x * BM;

    b1s[t] = b1[t];
    w1ss[t] = W1s[t];
    if (t < 16) { w2ss[t] = W2s[t]; b2s[t] = (t < 10) ? b2[t] : 0.f; }
    if (t < BM) sxs[t] = xs[row0 + t];

    // ---- stage xq tile into padded LDS (16 rows per wave) ----
    for (int i = 0; i < 16; ++i) {
        const int row = w * 16 + i;
        if (l < 49) {
            i32x4 v = *(const i32x4*)(xqg + (row0 + row) * 784 + 16 * l);
            *(i32x4*)(xq + row * XSTRIDE + 16 * l) = v;
        } else if (l < 53) {
            *(i32x4*)(xq + row * XSTRIDE + 16 * l) = (i32x4){0, 0, 0, 0};  // K-pad zeros
        }
    }
    __syncthreads();

    // ---- GEMM1: wave w owns cols w*64..w*64+63, all 64 rows ----
    i32x4 acc[4][4];
    #pragma unroll
    for (int mt = 0; mt < 4; ++mt)
        #pragma unroll
        for (int nt = 0; nt < 4; ++nt)
            acc[mt][nt] = (i32x4){0, 0, 0, 0};

    const int8_t* xbase = xq + lr * XSTRIDE + g * 16;
    const int8_t* wbase = W1q + (size_t)(w * 64 + lr) * 832 + g * 16;

    #pragma unroll
    for (int kk = 0; kk < 13; ++kk) {
        const int ko = kk * 64;
        i32x4 a[4], bv[4];
        #pragma unroll
        for (int mt = 0; mt < 4; ++mt) a[mt] = *(const i32x4*)(xbase + mt * 16 * XSTRIDE + ko);
        #pragma unroll
        for (int nt = 0; nt < 4; ++nt) bv[nt] = *(const i32x4*)(wbase + (size_t)nt * 16 * 832 + ko);
        #pragma unroll
        for (int mt = 0; mt < 4; ++mt)
            #pragma unroll
            for (int nt = 0; nt < 4; ++nt)
                acc[mt][nt] = __builtin_amdgcn_mfma_i32_16x16x64_i8(a[mt], bv[nt], acc[mt][nt], 0, 0, 0);
    }

    // ---- dequant + bias + relu (exact: |acc| < 2^24) ----
    float h[4][4][4];   // [mt][reg][nt]
    #pragma unroll
    for (int mt = 0; mt < 4; ++mt)
        #pragma unroll
        for (int nt = 0; nt < 4; ++nt)
            #pragma unroll
            for (int r = 0; r < 4; ++r) {
                const int rowl = mt * 16 + g * 4 + r;
                const int coll = w * 64 + nt * 16 + lr;
                float v = sxs[rowl] * w1ss[coll] * (float)acc[mt][nt][r] + b1s[coll];
                h[mt][r][nt] = fmaxf(v, 0.f);
            }

    // ---- per-row max of h ----
    #pragma unroll
    for (int mt = 0; mt < 4; ++mt)
        #pragma unroll
        for (int r = 0; r < 4; ++r) {
            float m = fmaxf(fmaxf(h[mt][r][0], h[mt][r][1]), fmaxf(h[mt][r][2], h[mt][r][3]));
            m = fmaxf(m, __shfl_xor(m, 1));
            m = fmaxf(m, __shfl_xor(m, 2));
            m = fmaxf(m, __shfl_xor(m, 4));
            m = fmaxf(m, __shfl_xor(m, 8));
            if (lr == 0) hpart[w][mt * 16 + g * 4 + r] = m;
        }
    __syncthreads();

    // ---- requantize h into hq ----
    #pragma unroll
    for (int mt = 0; mt < 4; ++mt)
        #pragma unroll
        for (int r = 0; r < 4; ++r) {
            const int rowl = mt * 16 + g * 4 + r;
            float hm = fmaxf(fmaxf(hpart[0][rowl], hpart[1][rowl]),
                             fmaxf(hpart[2][rowl], hpart[3][rowl]));
            float s2 = (hm == 0.f) ? 1.f : hm / 127.f;
            float ri2 = 1.f / s2;
            if (w == 0 && lr == 0) s2s[rowl] = s2;
            #pragma unroll
            for (int nt = 0; nt < 4; ++nt) {
                float q = fminf(fmaxf(rintf(h[mt][r][nt] * ri2), -127.f), 127.f);
                hq[rowl * HSTRIDE + w * 64 + nt * 16 + lr] = (int8_t)(int)q;
            }
        }
    __syncthreads();

    // ---- GEMM2 (each wave: 16 rows) + epilogue ----
    {
        i32x4 acc2 = (i32x4){0, 0, 0, 0};
        const int8_t* hbase = hq + (w * 16 + lr) * HSTRIDE + g * 16;
        const int8_t* w2base = W2q + lr * 256 + g * 16;
        #pragma unroll
        for (int kk = 0; kk < 4; ++kk) {
            i32x4 av = *(const i32x4*)(hbase + kk * 64);
            i32x4 bv = *(const i32x4*)(w2base + kk * 64);
            acc2 = __builtin_amdgcn_mfma_i32_16x16x64_i8(av, bv, acc2, 0, 0, 0);
        }
        if (lr < 10) {
            #pragma unroll
            for (int r = 0; r < 4; ++r) {
                const int rowl = w * 16 + g * 4 + r;
                float v = s2s[rowl] * w2ss[lr] * (float)acc2[r] + b2s[lr];
                out[(row0 + rowl) * 10 + lr] = v;
            }
        }
    }
}

extern "C" void kernel_launch(void* const* d_in, const int* in_sizes, int n_in,
                              void* d_out, int out_size, void* d_ws, size_t ws_size,
                              hipStream_t stream) {
    const float* x  = (const float*)d_in[0];
    const float* W1 = (const float*)d_in[1];
    const float* b1 = (const float*)d_in[2];
    const float* W2 = (const float*)d_in[3];
    const float* b2 = (const float*)d_in[4];
    float* out = (float*)d_out;

    int8_t* ws = (int8_t*)d_ws;
    int8_t* W1q = ws;                              // 212992 B
    float*  W1s = (float*)(ws + 212992);           // 1024 B
    int8_t* W2q = ws + 214016;                     // 4096 B
    float*  W2s = (float*)(ws + 218112);           // 64 B
    int8_t* xqg = ws + 220160;                     // 65536*784 = 51380224 B
    float*  xsc = (float*)(ws + 220160 + 51380224);// 262144 B

    quantW<<<272, 64, 0, stream>>>(W1, W2, W1q, W1s, W2q, W2s);
    quantX<<<2048, 256, 0, stream>>>(x, xqg, xsc);
    mlp<<<1024, 256, 0, stream>>>(xqg, xsc, W1q, W1s, b1, W2q, W2s, b2, out);
}

// Round 12
// 65.922 us; speedup vs baseline: 1.6719x; 1.3615x over previous
//
#include <hip/hip_runtime.h>
#include <cstdint>
#include <cstddef>

typedef __attribute__((ext_vector_type(4))) int i32x4;
typedef __attribute__((ext_vector_type(4))) float f32x4;

#define BM 32         // rows per block -> ~39 KB LDS -> 4 blocks/CU
#define XSTRIDE 848   // LDS bytes/row for xq: stride 212 dwords -> 2-way bank alias (free)
#define HSTRIDE 272   // LDS bytes/row for hq

static __device__ __forceinline__ int q4ri(f32x4 v, float ri) {
    float a = fminf(fmaxf(rintf(v.x * ri), -127.f), 127.f);
    float b = fminf(fmaxf(rintf(v.y * ri), -127.f), 127.f);
    float c = fminf(fmaxf(rintf(v.z * ri), -127.f), 127.f);
    float d = fminf(fmaxf(rintf(v.w * ri), -127.f), 127.f);
    return ((int)a & 255) | (((int)b & 255) << 8) | (((int)c & 255) << 16) | (((int)d & 255) << 24);
}
static __device__ __forceinline__ int q4div(f32x4 v, float s) {
    float a = fminf(fmaxf(rintf(v.x / s), -127.f), 127.f);
    float b = fminf(fmaxf(rintf(v.y / s), -127.f), 127.f);
    float c = fminf(fmaxf(rintf(v.z / s), -127.f), 127.f);
    float d = fminf(fmaxf(rintf(v.w / s), -127.f), 127.f);
    return ((int)a & 255) | (((int)b & 255) << 8) | (((int)c & 255) << 16) | (((int)d & 255) << 24);
}
static __device__ __forceinline__ float max4abs(f32x4 v) {
    return fmaxf(fmaxf(fabsf(v.x), fabsf(v.y)), fmaxf(fabsf(v.z), fabsf(v.w)));
}

// ---------------- weight quantization (tiny, runs once per call) --------------
__global__ __launch_bounds__(64) void quantW(const float* __restrict__ W1,
                                             const float* __restrict__ W2,
                                             int8_t* __restrict__ W1q, float* __restrict__ W1s,
                                             int8_t* __restrict__ W2q, float* __restrict__ W2s) {
    const int l = threadIdx.x;
    const int b = blockIdx.x;
    if (b < 256) {
        const float* wr = W1 + (size_t)b * 784;
        f32x4 v0 = *(const f32x4*)(wr + 4 * l);
        f32x4 v1 = *(const f32x4*)(wr + 4 * (l + 64));
        f32x4 v2 = *(const f32x4*)(wr + 4 * (l + 128));
        f32x4 v3 = (f32x4){0.f, 0.f, 0.f, 0.f};
        if (l < 4) v3 = *(const f32x4*)(wr + 4 * (192 + l));
        float m = fmaxf(fmaxf(max4abs(v0), max4abs(v1)), fmaxf(max4abs(v2), max4abs(v3)));
        #pragma unroll
        for (int off = 32; off >= 1; off >>= 1) m = fmaxf(m, __shfl_xor(m, off));
        float s = (m == 0.f) ? 1.f : m / 127.f;
        int* ow = (int*)(W1q + (size_t)b * 832);
        ow[l] = q4div(v0, s);
        ow[l + 64] = q4div(v1, s);
        ow[l + 128] = q4div(v2, s);
        if (l < 4) ow[192 + l] = q4div(v3, s);
        if (l >= 16 && l < 28) ow[196 + (l - 16)] = 0;
        if (l == 0) W1s[b] = s;
    } else {
        const int r = b - 256;
        int* ow = (int*)(W2q + (size_t)r * 256);
        if (r < 10) {
            f32x4 v0 = *(const f32x4*)(W2 + (size_t)r * 256 + 4 * l);
            float m = max4abs(v0);
            #pragma unroll
            for (int off = 32; off >= 1; off >>= 1) m = fmaxf(m, __shfl_xor(m, off));
            float s = (m == 0.f) ? 1.f : m / 127.f;
            ow[l] = q4div(v0, s);
            if (l == 0) W2s[r] = s;
        } else {
            ow[l] = 0;
            if (l == 0) W2s[r] = 1.f;
        }
    }
}

// ---------------- fused MLP: quantize x -> GEMM1 -> relu+requant -> GEMM2 ----
// 256 threads (4 waves), BM=32. Phase 1 stages ALL 8 rows per wave into
// registers up front (25 f32x4 loads in flight). Staging regs die before
// acc/h go live, so peak pressure stays under 128 (no spill). This structure
// measured 66.2 us total = ~3.4 TB/s effective read, at/above the platform's
// measured per-direction copy rate (m13: 6.29 TB/s bidirectional).
__global__ __launch_bounds__(256, 4) void fused_mlp(
    const float* __restrict__ x,
    const int8_t* __restrict__ W1q, const float* __restrict__ W1s, const float* __restrict__ b1,
    const int8_t* __restrict__ W2q, const float* __restrict__ W2s, const float* __restrict__ b2,
    float* __restrict__ out)
{
    __shared__ __align__(16) int8_t xq[BM * XSTRIDE];   // 27136 B
    __shared__ __align__(16) int8_t hq[BM * HSTRIDE];   //  8704 B
    __shared__ float sxs[BM];
    __shared__ float hpart[4][BM];
    __shared__ float s2s[BM];
    __shared__ float b1s[256], w1ss[256];
    __shared__ float b2s[16], w2ss[16];

    const int t = threadIdx.x;
    const int l = t & 63;
    const int w = t >> 6;            // wave 0..3
    const int g = l >> 4;            // 16-lane group 0..3
    const int lr = l & 15;
    const size_t row0 = (size_t)blockIdx.x * BM;

    b1s[t] = b1[t];
    w1ss[t] = W1s[t];
    if (t < 16) { w2ss[t] = W2s[t]; b2s[t] = (t < 10) ? b2[t] : 0.f; }

    // ---- phase 1: batch-load 8 rows/wave, then absmax+quantize into LDS ----
    {
        const int rbase = w * 8;
        const float* xb = x + (row0 + rbase) * 784;

        // tail chunk first: lanes 0..31 hold row (l>>2), floats 768+4*(l&3)..
        f32x4 Rt = (f32x4){0.f, 0.f, 0.f, 0.f};
        if (l < 32) Rt = *(const f32x4*)(xb + (size_t)(l >> 2) * 784 + 4 * (192 + (l & 3)));

        f32x4 R[8][3];
        #pragma unroll
        for (int r = 0; r < 8; ++r) {
            const float* xr = xb + (size_t)r * 784;
            R[r][0] = *(const f32x4*)(xr + 4 * l);
            R[r][1] = *(const f32x4*)(xr + 4 * (l + 64));
            R[r][2] = *(const f32x4*)(xr + 4 * (l + 128));
        }

        #pragma unroll
        for (int r = 0; r < 8; ++r) {
            float m = fmaxf(fmaxf(max4abs(R[r][0]), max4abs(R[r][1])), max4abs(R[r][2]));
            if ((l >> 2) == r) m = fmaxf(m, max4abs(Rt));
            #pragma unroll
            for (int off = 32; off >= 1; off >>= 1) m = fmaxf(m, __shfl_xor(m, off));
            float s = (m == 0.f) ? 1.f : m / 127.f;
            float ri = 1.f / s;
            const int row = rbase + r;
            int* xw = (int*)(xq + row * XSTRIDE);
            xw[l] = q4ri(R[r][0], ri);
            xw[l + 64] = q4ri(R[r][1], ri);
            xw[l + 128] = q4ri(R[r][2], ri);
            if ((l >> 2) == r) xw[192 + (l & 3)] = q4ri(Rt, ri);
            if (l >= 16 && l < 32) xw[196 + (l - 16)] = 0;   // zero K-pad bytes 784..847
            if (l == 0) sxs[row] = s;
        }
    }
    __syncthreads();

    // ---- phase 2: layer-1 GEMM. wave w owns cols w*64..w*64+63, rows 0..31 ----
    i32x4 acc[2][4];
    #pragma unroll
    for (int mt = 0; mt < 2; ++mt)
        #pragma unroll
        for (int nt = 0; nt < 4; ++nt)
            acc[mt][nt] = (i32x4){0, 0, 0, 0};

    const int8_t* xbase = xq + lr * XSTRIDE + g * 16;
    const int8_t* wbase = W1q + (size_t)(w * 64 + lr) * 832 + g * 16;

    #pragma unroll
    for (int kk = 0; kk < 13; ++kk) {
        const int ko = kk * 64;
        i32x4 a[2], bv[4];
        #pragma unroll
        for (int mt = 0; mt < 2; ++mt) a[mt] = *(const i32x4*)(xbase + mt * 16 * XSTRIDE + ko);
        #pragma unroll
        for (int nt = 0; nt < 4; ++nt) bv[nt] = *(const i32x4*)(wbase + (size_t)nt * 16 * 832 + ko);
        #pragma unroll
        for (int mt = 0; mt < 2; ++mt)
            #pragma unroll
            for (int nt = 0; nt < 4; ++nt)
                acc[mt][nt] = __builtin_amdgcn_mfma_i32_16x16x64_i8(a[mt], bv[nt], acc[mt][nt], 0, 0, 0);
    }

    // ---- phase 3: dequant + bias + relu (exact: |acc| < 2^24) ----
    float h[2][4][4];   // [mt][reg][nt]
    #pragma unroll
    for (int mt = 0; mt < 2; ++mt)
        #pragma unroll
        for (int nt = 0; nt < 4; ++nt)
            #pragma unroll
            for (int r = 0; r < 4; ++r) {
                const int rowl = mt * 16 + g * 4 + r;
                const int coll = w * 64 + nt * 16 + lr;
                float v = sxs[rowl] * w1ss[coll] * (float)acc[mt][nt][r] + b1s[coll];
                h[mt][r][nt] = fmaxf(v, 0.f);
            }

    // ---- phase 4: per-row max of h (h>=0 so max == absmax) ----
    #pragma unroll
    for (int mt = 0; mt < 2; ++mt)
        #pragma unroll
        for (int r = 0; r < 4; ++r) {
            float m = fmaxf(fmaxf(h[mt][r][0], h[mt][r][1]), fmaxf(h[mt][r][2], h[mt][r][3]));
            m = fmaxf(m, __shfl_xor(m, 1));
            m = fmaxf(m, __shfl_xor(m, 2));
            m = fmaxf(m, __shfl_xor(m, 4));
            m = fmaxf(m, __shfl_xor(m, 8));
            if (lr == 0) hpart[w][mt * 16 + g * 4 + r] = m;
        }
    __syncthreads();

    // ---- phase 5: requantize h into LDS hq ----
    #pragma unroll
    for (int mt = 0; mt < 2; ++mt)
        #pragma unroll
        for (int r = 0; r < 4; ++r) {
            const int rowl = mt * 16 + g * 4 + r;
            float hm = fmaxf(fmaxf(hpart[0][rowl], hpart[1][rowl]),
                             fmaxf(hpart[2][rowl], hpart[3][rowl]));
            float s2 = (hm == 0.f) ? 1.f : hm / 127.f;
            float ri2 = 1.f / s2;
            if (w == 0 && lr == 0) s2s[rowl] = s2;
            #pragma unroll
            for (int nt = 0; nt < 4; ++nt) {
                float q = fminf(fmaxf(rintf(h[mt][r][nt] * ri2), -127.f), 127.f);
                hq[rowl * HSTRIDE + w * 64 + nt * 16 + lr] = (int8_t)(int)q;
            }
        }
    __syncthreads();

    // ---- phase 6+7: layer-2 GEMM (waves 0..1, 16 rows each) + epilogue ----
    if (w < 2) {
        i32x4 acc2 = (i32x4){0, 0, 0, 0};
        const int8_t* hbase = hq + (w * 16 + lr) * HSTRIDE + g * 16;
        const int8_t* w2base = W2q + lr * 256 + g * 16;
        #pragma unroll
        for (int kk = 0; kk < 4; ++kk) {
            i32x4 av = *(const i32x4*)(hbase + kk * 64);
            i32x4 bv = *(const i32x4*)(w2base + kk * 64);
            acc2 = __builtin_amdgcn_mfma_i32_16x16x64_i8(av, bv, acc2, 0, 0, 0);
        }
        if (lr < 10) {
            #pragma unroll
            for (int r = 0; r < 4; ++r) {
                const int rowl = w * 16 + g * 4 + r;
                float v = s2s[rowl] * w2ss[lr] * (float)acc2[r] + b2s[lr];
                out[(row0 + rowl) * 10 + lr] = v;
            }
        }
    }
}

extern "C" void kernel_launch(void* const* d_in, const int* in_sizes, int n_in,
                              void* d_out, int out_size, void* d_ws, size_t ws_size,
                              hipStream_t stream) {
    const float* x  = (const float*)d_in[0];
    const float* W1 = (const float*)d_in[1];
    const float* b1 = (const float*)d_in[2];
    const float* W2 = (const float*)d_in[3];
    const float* b2 = (const float*)d_in[4];
    float* out = (float*)d_out;

    int8_t* ws = (int8_t*)d_ws;
    int8_t* W1q = ws;                            // 256*832   = 212992 B
    float*  W1s = (float*)(ws + 212992);         // 1024 B
    int8_t* W2q = ws + 214016;                   // 4096 B
    float*  W2s = (float*)(ws + 218112);         // 64 B

    quantW<<<272, 64, 0, stream>>>(W1, W2, W1q, W1s, W2q, W2s);
    fused_mlp<<<2048, 256, 0, stream>>>(x, W1q, W1s, b1, W2q, W2s, b2, out);
}